// Round 4
// baseline (572.171 us; speedup 1.0000x reference)
//
#include <hip/hip_runtime.h>
#include <math.h>

#define N_NODES 50000
#define N_EDGES 600000
#define D 128
#define EPS 1e-12f

#define SCAN_B 256
#define N_SCAN_BLOCKS ((N_NODES + SCAN_B - 1) / SCAN_B)   // 196

// ---------------- K1: edge cosine sim + degree count ------------------------
// qnorm computed per-block (cheap, removes a serial launch).
// two edges per wave: lanes 0-31 edge 2w, lanes 32-63 edge 2w+1, float4/lane.
__global__ void edge_sim_kernel(const float* __restrict__ ea,
                                const float* __restrict__ q,
                                const int* __restrict__ dst,
                                float* __restrict__ sim,
                                int* __restrict__ cnt) {
    __shared__ float qsh[D];
    __shared__ float ssh[2];
    int t = threadIdx.x;
    if (t < D) {
        float v = q[t];
        qsh[t] = v;
        float ss = v * v;
        #pragma unroll
        for (int off = 32; off > 0; off >>= 1) ss += __shfl_down(ss, off);
        if ((t & 63) == 0) ssh[t >> 6] = ss;
    }
    __syncthreads();
    float qinv = 1.0f / fmaxf(sqrtf(ssh[0] + ssh[1]), EPS);

    int gid  = blockIdx.x * blockDim.x + t;
    int wave = gid >> 6;
    if (wave >= N_EDGES / 2) return;
    int lane = t & 63;
    int half = lane >> 5;
    int l32  = lane & 31;
    int e    = 2 * wave + half;

    float4 v  = ((const float4*)(ea + (size_t)e * D))[l32];
    float4 qv = ((const float4*)qsh)[l32];
    float dot = v.x * qv.x + v.y * qv.y + v.z * qv.z + v.w * qv.w;
    float ss  = v.x * v.x + v.y * v.y + v.z * v.z + v.w * v.w;
    #pragma unroll
    for (int off = 16; off > 0; off >>= 1) {
        dot += __shfl_xor(dot, off);
        ss  += __shfl_xor(ss, off);
    }
    if (l32 == 0) {
        sim[e] = (dot * qinv) / fmaxf(sqrtf(ss), EPS);
        atomicAdd(&cnt[dst[e]], 1);
    }
}

// ---------------- K2: 3-phase exclusive scan of cnt -> row_ptr ---------------
__global__ void block_sum_kernel(const int* __restrict__ cnt, int* __restrict__ bsum) {
    __shared__ int s[SCAN_B];
    int t = threadIdx.x;
    int i = blockIdx.x * SCAN_B + t;
    s[t] = (i < N_NODES) ? cnt[i] : 0;
    __syncthreads();
    for (int off = SCAN_B / 2; off > 0; off >>= 1) {
        if (t < off) s[t] += s[t + off];
        __syncthreads();
    }
    if (t == 0) bsum[blockIdx.x] = s[0];
}

__global__ void scan_bsums_kernel(int* __restrict__ bsum) {
    __shared__ int s[SCAN_B];
    int t = threadIdx.x;
    int v = (t < N_SCAN_BLOCKS) ? bsum[t] : 0;
    s[t] = v;
    __syncthreads();
    for (int off = 1; off < SCAN_B; off <<= 1) {
        int a = (t >= off) ? s[t - off] : 0;
        __syncthreads();
        s[t] += a;
        __syncthreads();
    }
    if (t < N_SCAN_BLOCKS) bsum[t] = s[t] - v;   // exclusive
}

__global__ void scan_final_kernel(const int* __restrict__ cnt,
                                  const int* __restrict__ bsum,
                                  int* __restrict__ row_ptr,
                                  int* __restrict__ cursor,
                                  float* __restrict__ deg_inv) {
    __shared__ int s[SCAN_B];
    int t = threadIdx.x;
    int i = blockIdx.x * SCAN_B + t;
    int v = (i < N_NODES) ? cnt[i] : 0;
    s[t] = v;
    __syncthreads();
    for (int off = 1; off < SCAN_B; off <<= 1) {
        int a = (t >= off) ? s[t - off] : 0;
        __syncthreads();
        s[t] += a;
        __syncthreads();
    }
    if (i < N_NODES) {
        int rp = s[t] - v + bsum[blockIdx.x];
        row_ptr[i] = rp;
        cursor[i]  = rp;
        deg_inv[i] = 1.0f / fmaxf((float)v, 1.0f);
    }
    if (i == N_NODES - 1) row_ptr[N_NODES] = N_EDGES;
}

// ---------------- K3: fill CSR — packed {src, sim_bits} single 8B store ------
__global__ void fill_kernel(const int* __restrict__ src, const int* __restrict__ dst,
                            const float* __restrict__ sim,
                            int* __restrict__ cursor, int2* __restrict__ csr) {
    int e = blockIdx.x * blockDim.x + threadIdx.x;
    if (e >= N_EDGES) return;
    int idx = atomicAdd(&cursor[dst[e]], 1);
    csr[idx] = make_int2(src[e], __float_as_int(sim[e]));
}

// ---------------- K4: fused gather-aggregate + mean + residual blend --------
// TWO nodes per wave: each 32-lane half owns one node independently.
// CSR entries preloaded coalesced (8B/lane), broadcast per-edge via shfl
// within the half. float4 gathers, unroll-4 for 4 loads in flight.
__global__ void agg_kernel(const float* __restrict__ xin,
                           const int* __restrict__ row_ptr,
                           const int2* __restrict__ csr,
                           const float* __restrict__ deg_inv,
                           float* __restrict__ xout) {
    int gid  = blockIdx.x * blockDim.x + threadIdx.x;
    int wave = gid >> 6;
    int lane = threadIdx.x & 63;
    int half = lane >> 5;
    int l32  = lane & 31;
    int node = wave * 2 + half;
    if (node >= N_NODES) return;

    int beg = row_ptr[node];
    int end = row_ptr[node + 1];
    int n   = end - beg;

    // preload up to 32 packed (src, sim) entries — one coalesced 8B load
    int2 ce = make_int2(0, 0);
    if (l32 < n) ce = csr[beg + l32];

    float4 acc = make_float4(0.0f, 0.0f, 0.0f, 0.0f);
    int nn = (n < 32) ? n : 32;
    int base = half << 5;
    #pragma unroll 4
    for (int j = 0; j < nn; ++j) {
        int   s = __shfl(ce.x, base + j);
        float w = __int_as_float(__shfl(ce.y, base + j));
        float4 v = ((const float4*)(xin + (size_t)s * D))[l32];
        acc.x += v.x * w; acc.y += v.y * w; acc.z += v.z * w; acc.w += v.w * w;
    }
    // degree > 32 tail (Poisson(12): essentially never, kept for correctness)
    for (int j = 32; j < n; ++j) {
        int2 e2 = csr[beg + j];
        float w = __int_as_float(e2.y);
        float4 v = ((const float4*)(xin + (size_t)e2.x * D))[l32];
        acc.x += v.x * w; acc.y += v.y * w; acc.z += v.z * w; acc.w += v.w * w;
    }

    float di = deg_inv[node];
    float4 a = ((const float4*)(xin + (size_t)node * D))[l32];
    float4 o;
    o.x = 0.5f * a.x + 0.5f * acc.x * di;
    o.y = 0.5f * a.y + 0.5f * acc.y * di;
    o.z = 0.5f * a.z + 0.5f * acc.z * di;
    o.w = 0.5f * a.w + 0.5f * acc.w * di;
    ((float4*)(xout + (size_t)node * D))[l32] = o;
}

extern "C" void kernel_launch(void* const* d_in, const int* in_sizes, int n_in,
                              void* d_out, int out_size, void* d_ws, size_t ws_size,
                              hipStream_t stream) {
    const float* x  = (const float*)d_in[0];   // [N, D]
    const float* ea = (const float*)d_in[1];   // [E, D]
    const float* q  = (const float*)d_in[2];   // [D]
    const int*   ei = (const int*)d_in[3];     // [2, E]
    const int* src = ei;
    const int* dst = ei + N_EDGES;
    float* out = (float*)d_out;                // [N, D]

    // ---- workspace layout (x1 first; csr 8B-aligned right after) ----
    float* x1       = (float*)d_ws;                       // N*D floats
    int2*  csr      = (int2*)(x1 + (size_t)N_NODES * D);  // E int2
    float* sim      = (float*)(csr + N_EDGES);            // E
    float* deg_inv  = sim + N_EDGES;                      // N
    int*   cnt      = (int*)(deg_inv + N_NODES);          // N
    int*   row_ptr  = cnt + N_NODES;                      // N+1
    int*   cursor   = row_ptr + N_NODES + 1;              // N
    int*   bsum     = cursor + N_NODES;                   // 256

    hipMemsetAsync(cnt, 0, (size_t)N_NODES * sizeof(int), stream);

    {   // one wave per 2 edges
        long long threads = (long long)(N_EDGES / 2) * 64;
        int blocks = (int)((threads + 255) / 256);
        edge_sim_kernel<<<blocks, 256, 0, stream>>>(ea, q, dst, sim, cnt);
    }

    block_sum_kernel<<<N_SCAN_BLOCKS, SCAN_B, 0, stream>>>(cnt, bsum);
    scan_bsums_kernel<<<1, SCAN_B, 0, stream>>>(bsum);
    scan_final_kernel<<<N_SCAN_BLOCKS, SCAN_B, 0, stream>>>(cnt, bsum, row_ptr, cursor, deg_inv);

    fill_kernel<<<(N_EDGES + 255) / 256, 256, 0, stream>>>(src, dst, sim, cursor, csr);

    // two nodes per wave
    const long long agg_threads = (long long)((N_NODES + 1) / 2) * 64;
    const int agg_blocks = (int)((agg_threads + 255) / 256);
    // layer 1: x -> x1 ; layer 2: x1 -> out (no in-place hazard)
    agg_kernel<<<agg_blocks, 256, 0, stream>>>(x,  row_ptr, csr, deg_inv, x1);
    agg_kernel<<<agg_blocks, 256, 0, stream>>>(x1, row_ptr, csr, deg_inv, out);
}